// Round 2
// 1022.258 us; speedup vs baseline: 1.1495x; 1.1495x over previous
//
#include <hip/hip_runtime.h>

// MLA-style RopeAttention pipeline, all matmuls in bf16 MFMA (16x16x32).
// S=2048, D_MODEL=2048, NH=16, DH=128, LAT=512, VOCAB=32000.

typedef __bf16 bf16;
typedef __bf16 bf16x8 __attribute__((ext_vector_type(8)));
typedef float f32x4 __attribute__((ext_vector_type(4)));

__device__ __forceinline__ unsigned bfbits(float f) {
  unsigned u = __float_as_uint(f);
  return (u + 0x7fffu + ((u >> 16) & 1u)) >> 16;   // RNE truncate to bf16
}
__device__ __forceinline__ bf16 f2bf(float f) {
  union { unsigned short u; bf16 b; } cv;
  cv.u = (unsigned short)bfbits(f);
  return cv.b;
}

// async global->LDS, 16B per lane; LDS dest = wave-uniform base + lane*16.
__device__ __forceinline__ void async16(const void* g, const void* l) {
  typedef const __attribute__((address_space(1))) unsigned int* gp_t;
  typedef __attribute__((address_space(3))) unsigned int* lp_t;
  __builtin_amdgcn_global_load_lds((gp_t)(unsigned long long)g,
                                   (lp_t)(unsigned int)(unsigned long long)l,
                                   16, 0, 0);
}

__device__ __forceinline__ void storeC(float* p, float v) { *p = v; }
__device__ __forceinline__ void storeC(bf16* p, float v) { *p = f2bf(v); }

// ---------- elementwise fp32 -> bf16 (vec4) ----------
__global__ void k_convert(const float* __restrict__ in, bf16* __restrict__ out, int n4) {
  int i = blockIdx.x * 256 + threadIdx.x;
  if (i >= n4) return;
  float4 v = ((const float4*)in)[i];
  unsigned lo = bfbits(v.x) | (bfbits(v.y) << 16);
  unsigned hi = bfbits(v.z) | (bfbits(v.w) << 16);
  ((uint2*)out)[i] = make_uint2(lo, hi);
}

// ---------- transpose + convert: in (R x C) fp32 -> out (C x R) bf16 ----------
__global__ void k_transpose(const float* __restrict__ in, bf16* __restrict__ out,
                            int R, int C) {
  __shared__ float tile[32][33];
  int bc = blockIdx.x * 32, br = blockIdx.y * 32;
  int tx = threadIdx.x & 31, ty = threadIdx.x >> 5;  // ty 0..7
#pragma unroll
  for (int i = 0; i < 32; i += 8)
    tile[ty + i][tx] = in[(size_t)(br + ty + i) * C + bc + tx];
  __syncthreads();
#pragma unroll
  for (int i = 0; i < 32; i += 8)
    out[(size_t)(bc + ty + i) * R + br + tx] = f2bf(tile[tx][ty + i]);
}

// ---------- bf16 GEMM: C[M,N] = A[M,K] @ Bt[N,K]^T  (m97 structure) ----------
// 128x128 tile, BK=64, 4 waves each 64x64, global_load_lds staging.
// Kept for the small/medium GEMMs (down/up-projections).
template <typename OutT, bool TRANS>
__global__ __launch_bounds__(256, 2)
void k_gemm(const bf16* __restrict__ A, const bf16* __restrict__ Bt,
            OutT* __restrict__ C, int M, int N, int K) {
  __shared__ bf16 As[128 * 64];
  __shared__ bf16 Bs[128 * 64];
  const int tid = threadIdx.x;
  const int w = tid >> 6, lane = tid & 63;
  const int lm = lane & 15, quad = lane >> 4;
  const int m0 = blockIdx.x * 128;  // m-tile fastest: consecutive blocks share B-tile
  const int n0 = blockIdx.y * 128;
  const int wm = (w >> 1) * 64, wn = (w & 1) * 64;

  f32x4 acc[4][4] = {};
  const int ar = lane >> 3;        // row within 8-row chunk
  const int ac = (lane & 7) * 8;   // col element (8 bf16 = 16B)
  const bf16* Ab = A + (size_t)m0 * K + ac;
  const bf16* Bb = Bt + (size_t)n0 * K + ac;

  for (int k0 = 0; k0 < K; k0 += 64) {
#pragma unroll
    for (int j = 0; j < 4; ++j) {
      int ch = w * 4 + j;
      int row = ch * 8 + ar;
      async16(Ab + (size_t)row * K + k0, &As[ch * 512]);
      async16(Bb + (size_t)row * K + k0, &Bs[ch * 512]);
    }
    __syncthreads();
#pragma unroll
    for (int kk = 0; kk < 2; ++kk) {
      const int colb = kk * 32 + quad * 8;
      bf16x8 af[4], bfr[4];
#pragma unroll
      for (int i = 0; i < 4; ++i)
        af[i] = *(const bf16x8*)&As[(wm + i * 16 + lm) * 64 + colb];
#pragma unroll
      for (int j = 0; j < 4; ++j)
        bfr[j] = *(const bf16x8*)&Bs[(wn + j * 16 + lm) * 64 + colb];
#pragma unroll
      for (int i = 0; i < 4; ++i)
#pragma unroll
        for (int j = 0; j < 4; ++j)
          acc[i][j] = __builtin_amdgcn_mfma_f32_16x16x32_bf16(af[i], bfr[j], acc[i][j], 0, 0, 0);
    }
    __syncthreads();
  }

#pragma unroll
  for (int i = 0; i < 4; ++i) {
#pragma unroll
    for (int j = 0; j < 4; ++j) {
      f32x4 v = acc[i][j];
      const int row = m0 + wm + i * 16 + quad * 4;  // + r
      const int col = n0 + wn + j * 16 + lm;
      if constexpr (TRANS) {
        // write C^T[n][m], 4 contiguous m per lane, bf16 packed 8B
        unsigned lo = bfbits(v[0]) | (bfbits(v[1]) << 16);
        unsigned hi = bfbits(v[2]) | (bfbits(v[3]) << 16);
        *(uint2*)((bf16*)C + (size_t)col * M + row) = make_uint2(lo, hi);
      } else {
#pragma unroll
        for (int r = 0; r < 4; ++r)
          storeC(&C[(size_t)(row + r) * N + col], v[r]);
      }
    }
  }
}

// ---------- 256x256 8-phase bf16 GEMM (T1+T2+T3+T4+T5), fp32 out ----------
// C[M,N] = A[M,K] @ Bt[N,K]^T.  512 threads = 8 waves (2M x 4N), BK=64,
// 128 KiB LDS double-buffer, counted vmcnt(6) (never drain-0 in loop).
//
// Half-tile definitions are PHASE-MATCHED (rows grouped by first-reading
// quadrant) so the counted vmcnt ledger is exact:
//   A0' = rows [0,64)+[128,192)      read in ph1
//   A1' = rows [64,128)+[192,256)    read in ph3
//   B0' = rows with row%64 in [0,32)  read in ph1 (frags held in regs to ph4)
//   B1' = rows with row%64 in [32,64) read in ph2
// Steady-state stage schedule per tile u:
//   ph1: A1'(u+1)  ph2: A0'(u+2)  ph3: B0'(u+2)  ph4: B1'(u+2), vmcnt(6)
// At the ph4 wait the 3 youngest halves (u+2) may still fly; everything
// tile u+1 needs has landed.  Tail: u==NT-2 waits vmcnt(0).
//
// T2 swizzle (both sides): LDS dest linear (global_load_lds requirement);
// per-lane GLOBAL source chunk ^= row&7; ds_read applies the same XOR.
__global__ __launch_bounds__(512, 2)
void k_gemm256(const bf16* __restrict__ A, const bf16* __restrict__ Bt,
               float* __restrict__ C, int M, int N, int K) {
  __shared__ bf16 sh[2][2][256 * 64];   // [buf][A=0/B=1][row*64 + k] = 128 KB
  const int tid = threadIdx.x;
  const int lane = tid & 63, lm = lane & 15, quad = lane >> 4;
  const int wid = tid >> 6, wm = wid >> 2, wn = wid & 3;

  // T1: bijective XCD swizzle (grid % 8 == 0), m-fastest decomposition so
  // each XCD owns (nearly) exclusive n-panels of B.
  const int mt = M >> 8;
  const int qq = gridDim.x >> 3;
  const int swz = (blockIdx.x & 7) * qq + (blockIdx.x >> 3);
  const int m0 = (swz % mt) * 256, n0 = (swz / mt) * 256;
  const int NT = K >> 6;

  // staging geometry: one stg() call = 64 rows ([R0,R0+32) u [R1,R1+32)),
  // 512 threads x 16B = 8KB, linear LDS dest, swizzled global source.
  const int sr = (tid >> 3) & 31;
  const int sc8 = ((tid & 7) ^ (sr & 7)) << 3;   // T2 source swizzle
  const int shalf = tid >> 8;                    // wave-uniform
  const int lbase = ((tid >> 6) & 3) * 512;      // wave chunk within 64-row block
  const bf16* Ag = A + (size_t)(m0 + sr) * K + sc8;
  const bf16* Bg = Bt + (size_t)(n0 + sr) * K + sc8;

  auto stg = [&](const bf16* g, bf16* dst, int R0, int R1, int k0) {
    const int R = (shalf ? R1 : R0);
    async16(g + (size_t)R * K + k0, dst + R * 64 + lbase);
  };
  auto ldf = [&](const bf16* buf, int row, int col) -> bf16x8 {
    return *(const bf16x8*)&buf[row * 64 + (col ^ ((row & 7) << 3))];
  };

  // ---- prologue: tile0 (all 4 halves) + tile1 (A0',B0',B1') then vmcnt(6)
  stg(Ag, sh[0][0],   0,  32, 0);  stg(Ag, sh[0][0], 128, 160, 0);   // A0'(0)
  stg(Bg, sh[0][1],   0,  64, 0);  stg(Bg, sh[0][1], 128, 192, 0);   // B0'(0)
  stg(Bg, sh[0][1],  32,  96, 0);  stg(Bg, sh[0][1], 160, 224, 0);   // B1'(0)
  stg(Ag, sh[0][0],  64,  96, 0);  stg(Ag, sh[0][0], 192, 224, 0);   // A1'(0)
  if (NT > 1) {
    stg(Ag, sh[1][0],   0,  32, 64);  stg(Ag, sh[1][0], 128, 160, 64);
    stg(Bg, sh[1][1],   0,  64, 64);  stg(Bg, sh[1][1], 128, 192, 64);
    stg(Bg, sh[1][1],  32,  96, 64);  stg(Bg, sh[1][1], 160, 224, 64);
    asm volatile("s_waitcnt vmcnt(6)" ::: "memory");
  } else {
    asm volatile("s_waitcnt vmcnt(0)" ::: "memory");
  }
  __builtin_amdgcn_s_barrier();

  f32x4 acc[8][4] = {};
  for (int u = 0; u < NT; ++u) {
    const int bu = u & 1;
    const bf16* pA = sh[bu][0];
    const bf16* pB = sh[bu][1];
    bf16* nA = sh[bu ^ 1][0];   // A1'(u+1) target (other buffer)
    bf16* cA = sh[bu][0];       // tile u+2 targets (this buffer)
    bf16* cB = sh[bu][1];
    const int k1 = (u + 1) << 6, k2 = (u + 2) << 6;
    const bool st1 = (u + 1 < NT), st2 = (u + 2 < NT);

    bf16x8 af[4][2], b0[2][2], b1[2][2];

    // ---- phase 1: reads A0'+B0'; MFMA (mf0-3 x nf0-1); stage A1'(u+1)
#pragma unroll
    for (int mf = 0; mf < 4; ++mf)
#pragma unroll
      for (int kk = 0; kk < 2; ++kk)
        af[mf][kk] = ldf(pA, wm * 128 + mf * 16 + lm, kk * 32 + quad * 8);
#pragma unroll
    for (int nf = 0; nf < 2; ++nf)
#pragma unroll
      for (int kk = 0; kk < 2; ++kk)
        b0[nf][kk] = ldf(pB, wn * 64 + nf * 16 + lm, kk * 32 + quad * 8);
    if (st1) { stg(Ag, nA, 64, 96, k1); stg(Ag, nA, 192, 224, k1); }
    __builtin_amdgcn_s_barrier();
    asm volatile("s_waitcnt lgkmcnt(0)" ::: "memory");
    __builtin_amdgcn_s_setprio(1);
#pragma unroll
    for (int mf = 0; mf < 4; ++mf)
#pragma unroll
      for (int nf = 0; nf < 2; ++nf)
#pragma unroll
        for (int kk = 0; kk < 2; ++kk)
          acc[mf][nf] = __builtin_amdgcn_mfma_f32_16x16x32_bf16(af[mf][kk], b0[nf][kk], acc[mf][nf], 0, 0, 0);
    __builtin_amdgcn_s_setprio(0);
    __builtin_amdgcn_s_barrier();

    // ---- phase 2: reads B1'; MFMA (mf0-3 x nf2-3); stage A0'(u+2)
#pragma unroll
    for (int nf = 0; nf < 2; ++nf)
#pragma unroll
      for (int kk = 0; kk < 2; ++kk)
        b1[nf][kk] = ldf(pB, wn * 64 + (2 + nf) * 16 + lm, kk * 32 + quad * 8);
    if (st2) { stg(Ag, cA, 0, 32, k2); stg(Ag, cA, 128, 160, k2); }
    __builtin_amdgcn_s_barrier();
    asm volatile("s_waitcnt lgkmcnt(0)" ::: "memory");
    __builtin_amdgcn_s_setprio(1);
#pragma unroll
    for (int mf = 0; mf < 4; ++mf)
#pragma unroll
      for (int nf = 0; nf < 2; ++nf)
#pragma unroll
        for (int kk = 0; kk < 2; ++kk)
          acc[mf][2 + nf] = __builtin_amdgcn_mfma_f32_16x16x32_bf16(af[mf][kk], b1[nf][kk], acc[mf][2 + nf], 0, 0, 0);
    __builtin_amdgcn_s_setprio(0);
    __builtin_amdgcn_s_barrier();

    // ---- phase 3: reads A1'; MFMA (mf4-7 x nf2-3); stage B0'(u+2)
#pragma unroll
    for (int mf = 0; mf < 4; ++mf)
#pragma unroll
      for (int kk = 0; kk < 2; ++kk)
        af[mf][kk] = ldf(pA, wm * 128 + (4 + mf) * 16 + lm, kk * 32 + quad * 8);
    if (st2) { stg(Bg, cB, 0, 64, k2); stg(Bg, cB, 128, 192, k2); }
    __builtin_amdgcn_s_barrier();
    asm volatile("s_waitcnt lgkmcnt(0)" ::: "memory");
    __builtin_amdgcn_s_setprio(1);
#pragma unroll
    for (int mf = 0; mf < 4; ++mf)
#pragma unroll
      for (int nf = 0; nf < 2; ++nf)
#pragma unroll
        for (int kk = 0; kk < 2; ++kk)
          acc[4 + mf][2 + nf] = __builtin_amdgcn_mfma_f32_16x16x32_bf16(af[mf][kk], b1[nf][kk], acc[4 + mf][2 + nf], 0, 0, 0);
    __builtin_amdgcn_s_setprio(0);
    __builtin_amdgcn_s_barrier();

    // ---- phase 4: regs only; MFMA (mf4-7 x nf0-1); stage B1'(u+2); vmcnt
    if (st2) { stg(Bg, cB, 32, 96, k2); stg(Bg, cB, 160, 224, k2); }
    __builtin_amdgcn_s_barrier();
    __builtin_amdgcn_s_setprio(1);
#pragma unroll
    for (int mf = 0; mf < 4; ++mf)
#pragma unroll
      for (int nf = 0; nf < 2; ++nf)
#pragma unroll
        for (int kk = 0; kk < 2; ++kk)
          acc[4 + mf][nf] = __builtin_amdgcn_mfma_f32_16x16x32_bf16(af[mf][kk], b0[nf][kk], acc[4 + mf][nf], 0, 0, 0);
    __builtin_amdgcn_s_setprio(0);
    if (u < NT - 2) asm volatile("s_waitcnt vmcnt(6)" ::: "memory");
    else            asm volatile("s_waitcnt vmcnt(0)" ::: "memory");
    __builtin_amdgcn_s_barrier();
  }

  // ---- epilogue: C fp32 write (same lane mapping as k_gemm)
#pragma unroll
  for (int mf = 0; mf < 8; ++mf)
#pragma unroll
    for (int nf = 0; nf < 4; ++nf) {
      const int row = m0 + wm * 128 + mf * 16 + quad * 4;
      const int col = n0 + wn * 64 + nf * 16 + lm;
#pragma unroll
      for (int r = 0; r < 4; ++r)
        C[(size_t)(row + r) * N + col] = acc[mf][nf][r];
    }
}

// ---------- row LayerNorm, one wave per row (ldin = input row stride) ----------
__global__ void k_ln(const float* __restrict__ in, const float* __restrict__ g,
                     const float* __restrict__ b, bf16* __restrict__ obf,
                     float* __restrict__ of32, int C, int ldin, int bcast) {
  const int row = blockIdx.x, tid = threadIdx.x;
  const float* x = in + (size_t)row * ldin;
  float v[8];
  float s = 0.f, s2 = 0.f;
  int nv = 0;
  for (int c = tid * 4; c < C; c += 256) {
    float4 t = *(const float4*)(x + c);
    v[nv] = t.x; v[nv + 1] = t.y; v[nv + 2] = t.z; v[nv + 3] = t.w;
    s += t.x + t.y + t.z + t.w;
    s2 += t.x * t.x + t.y * t.y + t.z * t.z + t.w * t.w;
    nv += 4;
  }
#pragma unroll
  for (int d = 1; d < 64; d <<= 1) {
    s += __shfl_xor(s, d, 64);
    s2 += __shfl_xor(s2, d, 64);
  }
  const float invC = 1.0f / (float)C;
  const float mu = s * invC;
  const float rstd = rsqrtf(s2 * invC - mu * mu + 1e-5f);
  nv = 0;
  for (int c = tid * 4; c < C; c += 256) {
#pragma unroll
    for (int q = 0; q < 4; ++q) {
      float y = (v[nv + q] - mu) * rstd * g[c + q] + b[c + q];
      obf[(size_t)row * C + c + q] = f2bf(y);
      if (of32) {
        for (int k2 = 0; k2 < bcast; ++k2)
          of32[((size_t)row * bcast + k2) * C + c + q] = y;
      }
    }
    nv += 4;
  }
}

// ---------- RoPE over full 2048-dim rows (pairs d, d+1024) ----------
__global__ void k_rope(const float* __restrict__ pre, bf16* __restrict__ out) {
  const int s = blockIdx.x;
  const int j = threadIdx.x * 4;
  const float* rp = pre + (size_t)s * 2048;
  float4 x1 = *(const float4*)(rp + j);
  float4 x2 = *(const float4*)(rp + 1024 + j);
  float a1[4] = {x1.x, x1.y, x1.z, x1.w};
  float a2[4] = {x2.x, x2.y, x2.z, x2.w};
  float o1[4], o2[4];
#pragma unroll
  for (int q = 0; q < 4; ++q) {
    float invf = powf(20000.0f, -((float)(j + q)) * (1.0f / 1024.0f));
    float ang = (float)s * invf;
    float sn, cs;
    sincosf(ang, &sn, &cs);
    o1[q] = a1[q] * cs - a2[q] * sn;
    o2[q] = a1[q] * sn + a2[q] * cs;
  }
  unsigned l1 = bfbits(o1[0]) | (bfbits(o1[1]) << 16);
  unsigned h1 = bfbits(o1[2]) | (bfbits(o1[3]) << 16);
  unsigned l2 = bfbits(o2[0]) | (bfbits(o2[1]) << 16);
  unsigned h2 = bfbits(o2[2]) | (bfbits(o2[3]) << 16);
  *(uint2*)(out + (size_t)s * 2048 + j) = make_uint2(l1, h1);
  *(uint2*)(out + (size_t)s * 2048 + 1024 + j) = make_uint2(l2, h2);
}

// ---------- fused causal flash attention ----------
// block = (head h, q-tile of 64 rows), 4 waves x 16 q-rows, K-tiles of 64.
// Q (256-dim = q_c||q_r) resident in registers; K=(k_c||k_r), V^T staged to LDS.
__global__ __launch_bounds__(256, 2)
void k_attn(const bf16* __restrict__ q_c, const bf16* __restrict__ q_r,
            const bf16* __restrict__ k_c, const bf16* __restrict__ k_r,
            const bf16* __restrict__ v_t, bf16* __restrict__ out_h) {
  __shared__ bf16 Ks[64 * 256];   // [s][d] 32KB
  __shared__ bf16 Vs[128 * 64];   // [d][s] 16KB
  __shared__ bf16 Ps[64 * 64];    // 8KB
  const int tid = threadIdx.x;
  const int w = tid >> 6, lane = tid & 63;
  const int lm = lane & 15, quad = lane >> 4;
  const int qt = 31 - (blockIdx.x >> 4);  // heavy q-tiles first
  const int h = blockIdx.x & 15;

  // Q fragments (A-operand): row = lane&15, k = quad*8 + j within 32-chunk c
  const int qrow = qt * 64 + w * 16 + lm;
  bf16x8 qf[8];
#pragma unroll
  for (int c = 0; c < 8; ++c) {
    int d = c * 32 + quad * 8;
    const bf16* src = (d < 128) ? (q_c + (size_t)qrow * 2048 + h * 128 + d)
                                : (q_r + (size_t)qrow * 2048 + h * 128 + d - 128);
    qf[c] = *(const bf16x8*)src;
  }

  f32x4 o[8] = {};
  float mrow[4] = {-3e38f, -3e38f, -3e38f, -3e38f};
  float lrow[4] = {0.f, 0.f, 0.f, 0.f};

  const int ksr = lane >> 5;          // Ks chunk: 2 rows of 512B
  const int ksd = (lane & 31) * 8;    // d element 0..248
  const int vsr = lane >> 3;          // Vs chunk: 8 rows of 128B
  const int vss = (lane & 7) * 8;     // s element 0..56

  for (int kt = 0; kt <= qt; ++kt) {
#pragma unroll
    for (int j = 0; j < 8; ++j) {
      int ch = w * 8 + j;
      int srow = ch * 2 + ksr;
      const bf16* src = (ksd < 128)
          ? (k_c + (size_t)(kt * 64 + srow) * 2048 + h * 128 + ksd)
          : (k_r + (size_t)(kt * 64 + srow) * 128 + ksd - 128);
      async16(src, &Ks[ch * 512]);
    }
#pragma unroll
    for (int j = 0; j < 4; ++j) {
      int ch = w * 4 + j;
      int vrow = ch * 8 + vsr;
      async16(v_t + (size_t)(h * 128 + vrow) * 2048 + kt * 64 + vss, &Vs[ch * 512]);
    }
    __syncthreads();

    // S = Q K^T  (wave's 16 q-rows x 64 k-cols)
    f32x4 sa[4] = {};
#pragma unroll
    for (int c = 0; c < 8; ++c) {
#pragma unroll
      for (int ks = 0; ks < 4; ++ks) {
        bf16x8 kf = *(const bf16x8*)&Ks[(ks * 16 + lm) * 256 + c * 32 + quad * 8];
        sa[ks] = __builtin_amdgcn_mfma_f32_16x16x32_bf16(qf[c], kf, sa[ks], 0, 0, 0);
      }
    }
#pragma unroll
    for (int ks = 0; ks < 4; ++ks)
#pragma unroll
      for (int r = 0; r < 4; ++r)
        sa[ks][r] *= 0.0625f;  // 1/sqrt(2*DH)
    if (kt == qt) {            // diagonal tile: elementwise causal mask
#pragma unroll
      for (int ks = 0; ks < 4; ++ks)
#pragma unroll
        for (int r = 0; r < 4; ++r)
          if (ks * 16 + lm > w * 16 + quad * 4 + r) sa[ks][r] = -1e30f;
    }
    // online softmax; C-layout row = quad*4+reg, row-reduce = 16-lane shuffle
    float mx[4], alpha[4], rs[4];
#pragma unroll
    for (int r = 0; r < 4; ++r)
      mx[r] = fmaxf(fmaxf(sa[0][r], sa[1][r]), fmaxf(sa[2][r], sa[3][r]));
#pragma unroll
    for (int d = 1; d < 16; d <<= 1)
#pragma unroll
      for (int r = 0; r < 4; ++r)
        mx[r] = fmaxf(mx[r], __shfl_xor(mx[r], d, 64));
#pragma unroll
    for (int r = 0; r < 4; ++r) {
      float mn = fmaxf(mrow[r], mx[r]);
      alpha[r] = __expf(mrow[r] - mn);
      mrow[r] = mn;
      rs[r] = 0.f;
    }
#pragma unroll
    for (int ks = 0; ks < 4; ++ks)
#pragma unroll
      for (int r = 0; r < 4; ++r) {
        float p = __expf(sa[ks][r] - mrow[r]);
        rs[r] += p;
        Ps[(w * 16 + quad * 4 + r) * 64 + ks * 16 + lm] = f2bf(p);
      }
#pragma unroll
    for (int d = 1; d < 16; d <<= 1)
#pragma unroll
      for (int r = 0; r < 4; ++r)
        rs[r] += __shfl_xor(rs[r], d, 64);
#pragma unroll
    for (int r = 0; r < 4; ++r)
      lrow[r] = lrow[r] * alpha[r] + rs[r];
#pragma unroll
    for (int d8 = 0; d8 < 8; ++d8)
#pragma unroll
      for (int r = 0; r < 4; ++r)
        o[d8][r] *= alpha[r];
    __syncthreads();  // P visible (and orders vs other waves)

    // O += P @ V  (P from LDS as A-operand; V^T rows are d, contiguous s)
    bf16x8 pf[2];
#pragma unroll
    for (int kc = 0; kc < 2; ++kc)
      pf[kc] = *(const bf16x8*)&Ps[(w * 16 + lm) * 64 + kc * 32 + quad * 8];
#pragma unroll
    for (int d8 = 0; d8 < 8; ++d8) {
#pragma unroll
      for (int kc = 0; kc < 2; ++kc) {
        bf16x8 vf = *(const bf16x8*)&Vs[(d8 * 16 + lm) * 64 + kc * 32 + quad * 8];
        o[d8] = __builtin_amdgcn_mfma_f32_16x16x32_bf16(pf[kc], vf, o[d8], 0, 0, 0);
      }
    }
    __syncthreads();  // before next staging overwrites Ks/Vs
  }

  float inv_l[4];
#pragma unroll
  for (int r = 0; r < 4; ++r) inv_l[r] = 1.0f / lrow[r];
  bf16* Os = Ks;  // reuse 32KB as [64][128] output staging
#pragma unroll
  for (int d8 = 0; d8 < 8; ++d8)
#pragma unroll
    for (int r = 0; r < 4; ++r)
      Os[(w * 16 + quad * 4 + r) * 128 + d8 * 16 + lm] = f2bf(o[d8][r] * inv_l[r]);
  __syncthreads();
#pragma unroll
  for (int it = 0; it < 4; ++it) {
    int u = it * 256 + tid;
    int row = u >> 4, cb = u & 15;
    *(uint4*)(out_h + (size_t)(qt * 64 + row) * 2048 + h * 128 + cb * 8) =
        *(const uint4*)&Os[row * 128 + cb * 8];
  }
}

extern "C" void kernel_launch(void* const* d_in, const int* in_sizes, int n_in,
                              void* d_out, int out_size, void* d_ws, size_t ws_size,
                              hipStream_t stream) {
  const float* x    = (const float*)d_in[0];
  const float* Wdq  = (const float*)d_in[1];
  const float* Wdkv = (const float*)d_in[2];
  const float* Wuk  = (const float*)d_in[3];
  const float* Wuv  = (const float*)d_in[4];
  const float* Wuq  = (const float*)d_in[5];
  const float* Wqr  = (const float*)d_in[6];
  const float* Wkr  = (const float*)d_in[7];
  const float* Wo   = (const float*)d_in[8];
  const float* g_kv = (const float*)d_in[9];
  const float* b_kv = (const float*)d_in[10];
  const float* g_kr = (const float*)d_in[11];
  const float* b_kr = (const float*)d_in[12];

  float* out   = (float*)d_out;          // (2048, 32000)
  float* o_ckv = out + 65536000;         // (2048, 512)
  float* o_krh = o_ckv + 1048576;        // (2048, 16, 128)

  char* ws = (char*)d_ws;
  const size_t MB = 1ull << 20;
  // Early-phase buffers live in [0, 83MB). W_o^T (125MB) reuses [0,125MB) after
  // attention (all earlier buffers dead). out_heads at 126MB. Peak = 134MB.
  // WdqT / WdkvT / WkrT are contiguous: [1152][2048] for the merged down-proj.
  bf16*  x_bf   = (bf16*)(ws + 0);
  bf16*  WdqT   = (bf16*)(ws + 8 * MB);   // [512][2048]
  bf16*  WdkvT  = (bf16*)(ws + 10 * MB);  // [512][2048]
  bf16*  WkrT   = (bf16*)(ws + 12 * MB);  // [128][2048]
  bf16*  WuqT   = (bf16*)(ws + 13 * MB);
  bf16*  WukT   = (bf16*)(ws + 15 * MB);
  bf16*  WuvT   = (bf16*)(ws + 17 * MB);
  bf16*  WqrT   = (bf16*)(ws + 19 * MB);
  float* a_all  = (float*)(ws + 21 * MB); // (2048, 1152) = 9MB, ends at 30MB
  bf16*  cq_bf  = (bf16*)(ws + 30 * MB);
  bf16*  ckv_bf = (bf16*)(ws + 32 * MB);
  bf16*  kr_bf  = (bf16*)(ws + 34 * MB);
  bf16*  q_c    = (bf16*)(ws + 35 * MB);
  float* qrpre  = (float*)(ws + 43 * MB);
  bf16*  q_r    = (bf16*)(ws + 59 * MB);
  bf16*  k_c    = (bf16*)(ws + 67 * MB);
  bf16*  v_t    = (bf16*)(ws + 75 * MB);
  bf16*  WoT    = (bf16*)(ws + 0);
  bf16*  out_h  = (bf16*)(ws + 126 * MB);

  // 1) dtype conversion / weight transposes
  k_convert<<<4096, 256, 0, stream>>>(x, x_bf, 1048576);
  k_transpose<<<dim3(16, 64), 256, 0, stream>>>(Wdq, WdqT, 2048, 512);
  k_transpose<<<dim3(16, 64), 256, 0, stream>>>(Wdkv, WdkvT, 2048, 512);
  k_transpose<<<dim3(4, 64), 256, 0, stream>>>(Wkr, WkrT, 2048, 128);
  k_transpose<<<dim3(64, 16), 256, 0, stream>>>(Wuq, WuqT, 512, 2048);
  k_transpose<<<dim3(64, 16), 256, 0, stream>>>(Wuk, WukT, 512, 2048);
  k_transpose<<<dim3(64, 16), 256, 0, stream>>>(Wuv, WuvT, 512, 2048);
  k_transpose<<<dim3(64, 16), 256, 0, stream>>>(Wqr, WqrT, 512, 2048);

  // 2) merged down-projection (K=2048): [dq | dkv | kr] in one GEMM, N=1152
  k_gemm<float, false><<<dim3(16, 9), 256, 0, stream>>>(x_bf, WdqT, a_all, 2048, 1152, 2048);

  // 3) layernorms (c_kv and k_r_h go straight to d_out); inputs strided in a_all
  k_ln<<<2048, 64, 0, stream>>>(a_all +    0, g_kv, b_kv, cq_bf, (float*)nullptr, 512, 1152, 1);
  k_ln<<<2048, 64, 0, stream>>>(a_all +  512, g_kv, b_kv, ckv_bf, o_ckv, 512, 1152, 1);
  k_ln<<<2048, 64, 0, stream>>>(a_all + 1024, g_kr, b_kr, kr_bf, o_krh, 128, 1152, 16);

  // 4) up-projections (K=512); V written transposed (d, s) for PV B-operand
  k_gemm<bf16, false><<<dim3(16, 16), 256, 0, stream>>>(cq_bf, WuqT, q_c, 2048, 2048, 512);
  k_gemm<float, false><<<dim3(16, 16), 256, 0, stream>>>(cq_bf, WqrT, qrpre, 2048, 2048, 512);
  k_gemm<bf16, false><<<dim3(16, 16), 256, 0, stream>>>(ckv_bf, WukT, k_c, 2048, 2048, 512);
  k_gemm<bf16, true><<<dim3(16, 16), 256, 0, stream>>>(ckv_bf, WuvT, v_t, 2048, 2048, 512);

  // 5) rope on full 2048-dim rows
  k_rope<<<2048, 256, 0, stream>>>(qrpre, q_r);

  // 6) fused causal attention -> out_heads
  k_attn<<<512, 256, 0, stream>>>(q_c, q_r, k_c, kr_bf, v_t, out_h);

  // 7) vocab projection (dominant GEMM): transpose W_o (reusing dead ws), then
  //    256x256 8-phase pipelined GEMM (grid 8x125 = 1000, %8==0 for T1 swizzle)
  k_transpose<<<dim3(1000, 64), 256, 0, stream>>>(Wo, WoT, 2048, 32000);
  k_gemm256<<<1000, 512, 0, stream>>>(out_h, WoT, out, 2048, 32000, 2048);

  (void)in_sizes; (void)n_in; (void)out_size; (void)ws_size;
}

// Round 3
// 948.672 us; speedup vs baseline: 1.2387x; 1.0776x over previous
//
#include <hip/hip_runtime.h>

// MLA-style RopeAttention pipeline, all matmuls in bf16 MFMA (16x16x32).
// S=2048, D_MODEL=2048, NH=16, DH=128, LAT=512, VOCAB=32000.

typedef __bf16 bf16;
typedef __bf16 bf16x8 __attribute__((ext_vector_type(8)));
typedef float f32x4 __attribute__((ext_vector_type(4)));

__device__ __forceinline__ unsigned bfbits(float f) {
  unsigned u = __float_as_uint(f);
  return (u + 0x7fffu + ((u >> 16) & 1u)) >> 16;   // RNE truncate to bf16
}
__device__ __forceinline__ bf16 f2bf(float f) {
  union { unsigned short u; bf16 b; } cv;
  cv.u = (unsigned short)bfbits(f);
  return cv.b;
}

// async global->LDS, 16B per lane; LDS dest = wave-uniform base + lane*16.
__device__ __forceinline__ void async16(const void* g, const void* l) {
  typedef const __attribute__((address_space(1))) unsigned int* gp_t;
  typedef __attribute__((address_space(3))) unsigned int* lp_t;
  __builtin_amdgcn_global_load_lds((gp_t)(unsigned long long)g,
                                   (lp_t)(unsigned int)(unsigned long long)l,
                                   16, 0, 0);
}

__device__ __forceinline__ void storeC(float* p, float v) { *p = v; }
__device__ __forceinline__ void storeC(bf16* p, float v) { *p = f2bf(v); }

// ---------- elementwise fp32 -> bf16 (vec4) ----------
__global__ void k_convert(const float* __restrict__ in, bf16* __restrict__ out, int n4) {
  int i = blockIdx.x * 256 + threadIdx.x;
  if (i >= n4) return;
  float4 v = ((const float4*)in)[i];
  unsigned lo = bfbits(v.x) | (bfbits(v.y) << 16);
  unsigned hi = bfbits(v.z) | (bfbits(v.w) << 16);
  ((uint2*)out)[i] = make_uint2(lo, hi);
}

// ---------- transpose + convert: in (R x C) fp32 -> out (C x R) bf16 ----------
__global__ void k_transpose(const float* __restrict__ in, bf16* __restrict__ out,
                            int R, int C) {
  __shared__ float tile[32][33];
  int bc = blockIdx.x * 32, br = blockIdx.y * 32;
  int tx = threadIdx.x & 31, ty = threadIdx.x >> 5;  // ty 0..7
#pragma unroll
  for (int i = 0; i < 32; i += 8)
    tile[ty + i][tx] = in[(size_t)(br + ty + i) * C + bc + tx];
  __syncthreads();
#pragma unroll
  for (int i = 0; i < 32; i += 8)
    out[(size_t)(bc + ty + i) * R + br + tx] = f2bf(tile[tx][ty + i]);
}

// ---------- bf16 GEMM: C[M,N] = A[M,K] @ Bt[N,K]^T  (m97 structure) ----------
// 128x128 tile, BK=64, 4 waves each 64x64, global_load_lds staging.
// Kept for the small/medium GEMMs (down/up-projections).
template <typename OutT, bool TRANS>
__global__ __launch_bounds__(256, 2)
void k_gemm(const bf16* __restrict__ A, const bf16* __restrict__ Bt,
            OutT* __restrict__ C, int M, int N, int K) {
  __shared__ bf16 As[128 * 64];
  __shared__ bf16 Bs[128 * 64];
  const int tid = threadIdx.x;
  const int w = tid >> 6, lane = tid & 63;
  const int lm = lane & 15, quad = lane >> 4;
  const int m0 = blockIdx.x * 128;  // m-tile fastest: consecutive blocks share B-tile
  const int n0 = blockIdx.y * 128;
  const int wm = (w >> 1) * 64, wn = (w & 1) * 64;

  f32x4 acc[4][4] = {};
  const int ar = lane >> 3;        // row within 8-row chunk
  const int ac = (lane & 7) * 8;   // col element (8 bf16 = 16B)
  const bf16* Ab = A + (size_t)m0 * K + ac;
  const bf16* Bb = Bt + (size_t)n0 * K + ac;

  for (int k0 = 0; k0 < K; k0 += 64) {
#pragma unroll
    for (int j = 0; j < 4; ++j) {
      int ch = w * 4 + j;
      int row = ch * 8 + ar;
      async16(Ab + (size_t)row * K + k0, &As[ch * 512]);
      async16(Bb + (size_t)row * K + k0, &Bs[ch * 512]);
    }
    __syncthreads();
#pragma unroll
    for (int kk = 0; kk < 2; ++kk) {
      const int colb = kk * 32 + quad * 8;
      bf16x8 af[4], bfr[4];
#pragma unroll
      for (int i = 0; i < 4; ++i)
        af[i] = *(const bf16x8*)&As[(wm + i * 16 + lm) * 64 + colb];
#pragma unroll
      for (int j = 0; j < 4; ++j)
        bfr[j] = *(const bf16x8*)&Bs[(wn + j * 16 + lm) * 64 + colb];
#pragma unroll
      for (int i = 0; i < 4; ++i)
#pragma unroll
        for (int j = 0; j < 4; ++j)
          acc[i][j] = __builtin_amdgcn_mfma_f32_16x16x32_bf16(af[i], bfr[j], acc[i][j], 0, 0, 0);
    }
    __syncthreads();
  }

#pragma unroll
  for (int i = 0; i < 4; ++i) {
#pragma unroll
    for (int j = 0; j < 4; ++j) {
      f32x4 v = acc[i][j];
      const int row = m0 + wm + i * 16 + quad * 4;  // + r
      const int col = n0 + wn + j * 16 + lm;
      if constexpr (TRANS) {
        // write C^T[n][m], 4 contiguous m per lane, bf16 packed 8B
        unsigned lo = bfbits(v[0]) | (bfbits(v[1]) << 16);
        unsigned hi = bfbits(v[2]) | (bfbits(v[3]) << 16);
        *(uint2*)((bf16*)C + (size_t)col * M + row) = make_uint2(lo, hi);
      } else {
#pragma unroll
        for (int r = 0; r < 4; ++r)
          storeC(&C[(size_t)(row + r) * N + col], v[r]);
      }
    }
  }
}

// ---------- 256x256 8-phase bf16 GEMM (T1+T2+T3+T4+T5), fp32 out ----------
// C[M,N] = A[M,K] @ Bt[N,K]^T.  512 threads = 8 waves (2M x 4N), BK=64,
// 128 KiB LDS double-buffer, counted vmcnt(6) (never drain-0 in loop).
//
// Half-tile definitions are PHASE-MATCHED (rows grouped by first-reading
// quadrant) so the counted vmcnt ledger is exact:
//   A0' = rows [0,64)+[128,192)      read in ph1
//   A1' = rows [64,128)+[192,256)    read in ph3
//   B0' = rows with row%64 in [0,32)  read in ph1 (frags held in regs to ph4)
//   B1' = rows with row%64 in [32,64) read in ph2
// Steady-state stage schedule per tile u:
//   ph1: A1'(u+1)  ph2: A0'(u+2)  ph3: B0'(u+2)  ph4: B1'(u+2), vmcnt(6)
// At the ph4 wait the 3 youngest halves (u+2) may still fly; everything
// tile u+1 needs has landed.  Tail: u==NT-2 waits vmcnt(0).
//
// T2 swizzle (both sides): LDS dest linear (global_load_lds requirement);
// per-lane GLOBAL source chunk ^= row&7; ds_read applies the same XOR.
__global__ __launch_bounds__(512, 2)
void k_gemm256(const bf16* __restrict__ A, const bf16* __restrict__ Bt,
               float* __restrict__ C, int M, int N, int K) {
  __shared__ bf16 sh[2][2][256 * 64];   // [buf][A=0/B=1][row*64 + k] = 128 KB
  const int tid = threadIdx.x;
  const int lane = tid & 63, lm = lane & 15, quad = lane >> 4;
  const int wid = tid >> 6, wm = wid >> 2, wn = wid & 3;

  // T1: bijective XCD swizzle (grid % 8 == 0), m-fastest decomposition so
  // each XCD owns (nearly) exclusive n-panels of B.
  const int mt = M >> 8;
  const int qq = gridDim.x >> 3;
  const int swz = (blockIdx.x & 7) * qq + (blockIdx.x >> 3);
  const int m0 = (swz % mt) * 256, n0 = (swz / mt) * 256;
  const int NT = K >> 6;

  // staging geometry: one stg() call = 64 rows ([R0,R0+32) u [R1,R1+32)),
  // 512 threads x 16B = 8KB, linear LDS dest, swizzled global source.
  const int sr = (tid >> 3) & 31;
  const int sc8 = ((tid & 7) ^ (sr & 7)) << 3;   // T2 source swizzle
  const int shalf = tid >> 8;                    // wave-uniform
  const int lbase = ((tid >> 6) & 3) * 512;      // wave chunk within 64-row block
  const bf16* Ag = A + (size_t)(m0 + sr) * K + sc8;
  const bf16* Bg = Bt + (size_t)(n0 + sr) * K + sc8;

  auto stg = [&](const bf16* g, bf16* dst, int R0, int R1, int k0) {
    const int R = (shalf ? R1 : R0);
    async16(g + (size_t)R * K + k0, dst + R * 64 + lbase);
  };
  auto ldf = [&](const bf16* buf, int row, int col) -> bf16x8 {
    return *(const bf16x8*)&buf[row * 64 + (col ^ ((row & 7) << 3))];
  };

  // ---- prologue: tile0 (all 4 halves) + tile1 (A0',B0',B1') then vmcnt(6)
  stg(Ag, sh[0][0],   0,  32, 0);  stg(Ag, sh[0][0], 128, 160, 0);   // A0'(0)
  stg(Bg, sh[0][1],   0,  64, 0);  stg(Bg, sh[0][1], 128, 192, 0);   // B0'(0)
  stg(Bg, sh[0][1],  32,  96, 0);  stg(Bg, sh[0][1], 160, 224, 0);   // B1'(0)
  stg(Ag, sh[0][0],  64,  96, 0);  stg(Ag, sh[0][0], 192, 224, 0);   // A1'(0)
  if (NT > 1) {
    stg(Ag, sh[1][0],   0,  32, 64);  stg(Ag, sh[1][0], 128, 160, 64);
    stg(Bg, sh[1][1],   0,  64, 64);  stg(Bg, sh[1][1], 128, 192, 64);
    stg(Bg, sh[1][1],  32,  96, 64);  stg(Bg, sh[1][1], 160, 224, 64);
    asm volatile("s_waitcnt vmcnt(6)" ::: "memory");
  } else {
    asm volatile("s_waitcnt vmcnt(0)" ::: "memory");
  }
  __builtin_amdgcn_s_barrier();

  f32x4 acc[8][4] = {};
  for (int u = 0; u < NT; ++u) {
    const int bu = u & 1;
    const bf16* pA = sh[bu][0];
    const bf16* pB = sh[bu][1];
    bf16* nA = sh[bu ^ 1][0];   // A1'(u+1) target (other buffer)
    bf16* cA = sh[bu][0];       // tile u+2 targets (this buffer)
    bf16* cB = sh[bu][1];
    const int k1 = (u + 1) << 6, k2 = (u + 2) << 6;
    const bool st1 = (u + 1 < NT), st2 = (u + 2 < NT);

    bf16x8 af[4][2], b0[2][2], b1[2][2];

    // ---- phase 1: reads A0'+B0'; MFMA (mf0-3 x nf0-1); stage A1'(u+1)
#pragma unroll
    for (int mf = 0; mf < 4; ++mf)
#pragma unroll
      for (int kk = 0; kk < 2; ++kk)
        af[mf][kk] = ldf(pA, wm * 128 + mf * 16 + lm, kk * 32 + quad * 8);
#pragma unroll
    for (int nf = 0; nf < 2; ++nf)
#pragma unroll
      for (int kk = 0; kk < 2; ++kk)
        b0[nf][kk] = ldf(pB, wn * 64 + nf * 16 + lm, kk * 32 + quad * 8);
    if (st1) { stg(Ag, nA, 64, 96, k1); stg(Ag, nA, 192, 224, k1); }
    __builtin_amdgcn_s_barrier();
    asm volatile("s_waitcnt lgkmcnt(0)" ::: "memory");
    __builtin_amdgcn_s_setprio(1);
#pragma unroll
    for (int mf = 0; mf < 4; ++mf)
#pragma unroll
      for (int nf = 0; nf < 2; ++nf)
#pragma unroll
        for (int kk = 0; kk < 2; ++kk)
          acc[mf][nf] = __builtin_amdgcn_mfma_f32_16x16x32_bf16(af[mf][kk], b0[nf][kk], acc[mf][nf], 0, 0, 0);
    __builtin_amdgcn_s_setprio(0);
    __builtin_amdgcn_s_barrier();

    // ---- phase 2: reads B1'; MFMA (mf0-3 x nf2-3); stage A0'(u+2)
#pragma unroll
    for (int nf = 0; nf < 2; ++nf)
#pragma unroll
      for (int kk = 0; kk < 2; ++kk)
        b1[nf][kk] = ldf(pB, wn * 64 + (2 + nf) * 16 + lm, kk * 32 + quad * 8);
    if (st2) { stg(Ag, cA, 0, 32, k2); stg(Ag, cA, 128, 160, k2); }
    __builtin_amdgcn_s_barrier();
    asm volatile("s_waitcnt lgkmcnt(0)" ::: "memory");
    __builtin_amdgcn_s_setprio(1);
#pragma unroll
    for (int mf = 0; mf < 4; ++mf)
#pragma unroll
      for (int nf = 0; nf < 2; ++nf)
#pragma unroll
        for (int kk = 0; kk < 2; ++kk)
          acc[mf][2 + nf] = __builtin_amdgcn_mfma_f32_16x16x32_bf16(af[mf][kk], b1[nf][kk], acc[mf][2 + nf], 0, 0, 0);
    __builtin_amdgcn_s_setprio(0);
    __builtin_amdgcn_s_barrier();

    // ---- phase 3: reads A1'; MFMA (mf4-7 x nf2-3); stage B0'(u+2)
#pragma unroll
    for (int mf = 0; mf < 4; ++mf)
#pragma unroll
      for (int kk = 0; kk < 2; ++kk)
        af[mf][kk] = ldf(pA, wm * 128 + (4 + mf) * 16 + lm, kk * 32 + quad * 8);
    if (st2) { stg(Bg, cB, 0, 64, k2); stg(Bg, cB, 128, 192, k2); }
    __builtin_amdgcn_s_barrier();
    asm volatile("s_waitcnt lgkmcnt(0)" ::: "memory");
    __builtin_amdgcn_s_setprio(1);
#pragma unroll
    for (int mf = 0; mf < 4; ++mf)
#pragma unroll
      for (int nf = 0; nf < 2; ++nf)
#pragma unroll
        for (int kk = 0; kk < 2; ++kk)
          acc[4 + mf][2 + nf] = __builtin_amdgcn_mfma_f32_16x16x32_bf16(af[mf][kk], b1[nf][kk], acc[4 + mf][2 + nf], 0, 0, 0);
    __builtin_amdgcn_s_setprio(0);
    __builtin_amdgcn_s_barrier();

    // ---- phase 4: regs only; MFMA (mf4-7 x nf0-1); stage B1'(u+2); vmcnt
    if (st2) { stg(Bg, cB, 32, 96, k2); stg(Bg, cB, 160, 224, k2); }
    __builtin_amdgcn_s_barrier();
    __builtin_amdgcn_s_setprio(1);
#pragma unroll
    for (int mf = 0; mf < 4; ++mf)
#pragma unroll
      for (int nf = 0; nf < 2; ++nf)
#pragma unroll
        for (int kk = 0; kk < 2; ++kk)
          acc[4 + mf][nf] = __builtin_amdgcn_mfma_f32_16x16x32_bf16(af[mf][kk], b0[nf][kk], acc[4 + mf][nf], 0, 0, 0);
    __builtin_amdgcn_s_setprio(0);
    if (u < NT - 2) asm volatile("s_waitcnt vmcnt(6)" ::: "memory");
    else            asm volatile("s_waitcnt vmcnt(0)" ::: "memory");
    __builtin_amdgcn_s_barrier();
  }

  // ---- epilogue: C fp32 write (same lane mapping as k_gemm)
#pragma unroll
  for (int mf = 0; mf < 8; ++mf)
#pragma unroll
    for (int nf = 0; nf < 4; ++nf) {
      const int row = m0 + wm * 128 + mf * 16 + quad * 4;
      const int col = n0 + wn * 64 + nf * 16 + lm;
#pragma unroll
      for (int r = 0; r < 4; ++r)
        C[(size_t)(row + r) * N + col] = acc[mf][nf][r];
    }
}

// ---------- row LayerNorm, one wave per row (ldin = input row stride) ----------
__global__ void k_ln(const float* __restrict__ in, const float* __restrict__ g,
                     const float* __restrict__ b, bf16* __restrict__ obf,
                     float* __restrict__ of32, int C, int ldin, int bcast) {
  const int row = blockIdx.x, tid = threadIdx.x;
  const float* x = in + (size_t)row * ldin;
  float v[8];
  float s = 0.f, s2 = 0.f;
  int nv = 0;
  for (int c = tid * 4; c < C; c += 256) {
    float4 t = *(const float4*)(x + c);
    v[nv] = t.x; v[nv + 1] = t.y; v[nv + 2] = t.z; v[nv + 3] = t.w;
    s += t.x + t.y + t.z + t.w;
    s2 += t.x * t.x + t.y * t.y + t.z * t.z + t.w * t.w;
    nv += 4;
  }
#pragma unroll
  for (int d = 1; d < 64; d <<= 1) {
    s += __shfl_xor(s, d, 64);
    s2 += __shfl_xor(s2, d, 64);
  }
  const float invC = 1.0f / (float)C;
  const float mu = s * invC;
  const float rstd = rsqrtf(s2 * invC - mu * mu + 1e-5f);
  nv = 0;
  for (int c = tid * 4; c < C; c += 256) {
#pragma unroll
    for (int q = 0; q < 4; ++q) {
      float y = (v[nv + q] - mu) * rstd * g[c + q] + b[c + q];
      obf[(size_t)row * C + c + q] = f2bf(y);
      if (of32) {
        for (int k2 = 0; k2 < bcast; ++k2)
          of32[((size_t)row * bcast + k2) * C + c + q] = y;
      }
    }
    nv += 4;
  }
}

// ---------- RoPE over full 2048-dim rows (pairs d, d+1024) ----------
__global__ void k_rope(const float* __restrict__ pre, bf16* __restrict__ out) {
  const int s = blockIdx.x;
  const int j = threadIdx.x * 4;
  const float* rp = pre + (size_t)s * 2048;
  float4 x1 = *(const float4*)(rp + j);
  float4 x2 = *(const float4*)(rp + 1024 + j);
  float a1[4] = {x1.x, x1.y, x1.z, x1.w};
  float a2[4] = {x2.x, x2.y, x2.z, x2.w};
  float o1[4], o2[4];
#pragma unroll
  for (int q = 0; q < 4; ++q) {
    float invf = powf(20000.0f, -((float)(j + q)) * (1.0f / 1024.0f));
    float ang = (float)s * invf;
    float sn, cs;
    sincosf(ang, &sn, &cs);
    o1[q] = a1[q] * cs - a2[q] * sn;
    o2[q] = a1[q] * sn + a2[q] * cs;
  }
  unsigned l1 = bfbits(o1[0]) | (bfbits(o1[1]) << 16);
  unsigned h1 = bfbits(o1[2]) | (bfbits(o1[3]) << 16);
  unsigned l2 = bfbits(o2[0]) | (bfbits(o2[1]) << 16);
  unsigned h2 = bfbits(o2[2]) | (bfbits(o2[3]) << 16);
  *(uint2*)(out + (size_t)s * 2048 + j) = make_uint2(l1, h1);
  *(uint2*)(out + (size_t)s * 2048 + 1024 + j) = make_uint2(l2, h2);
}

// ---------- fused causal flash attention ----------
// block = (head h, q-tile of 64 rows), 4 waves x 16 q-rows, K-tiles of 64.
// Q (256-dim = q_c||q_r) resident in registers; K=(k_c||k_r), V^T staged to LDS.
//
// T2 both-sides XOR swizzle on ALL LDS tiles (16B-slot granularity,
// slot' = slot ^ (local_row & 7)):
//  - Ks/Vs: staged via global_load_lds (dest linear) -> XOR applied to the
//    per-lane GLOBAL source column; ds_read applies the same XOR.
//  - Ps: register stores -> XOR on both store and read indices.
// Without this, row strides of 512B/128B put every quad's 16 lanes on the
// same 4 banks (16-way conflict) for ALL QK^T / PV operand reads.
__global__ __launch_bounds__(256, 2)
void k_attn(const bf16* __restrict__ q_c, const bf16* __restrict__ q_r,
            const bf16* __restrict__ k_c, const bf16* __restrict__ k_r,
            const bf16* __restrict__ v_t, bf16* __restrict__ out_h) {
  __shared__ bf16 Ks[64 * 256];   // [s][d] 32KB, 32 slots/row
  __shared__ bf16 Vs[128 * 64];   // [d][s] 16KB, 8 slots/row
  __shared__ bf16 Ps[64 * 64];    // 8KB, 8 slots/row
  const int tid = threadIdx.x;
  const int w = tid >> 6, lane = tid & 63;
  const int lm = lane & 15, quad = lane >> 4;
  const int lm7 = lm & 7;
  const int qt = 31 - (blockIdx.x >> 4);  // heavy q-tiles first
  const int h = blockIdx.x & 15;

  // Q fragments (A-operand): row = lane&15, k = quad*8 + j within 32-chunk c
  const int qrow = qt * 64 + w * 16 + lm;
  bf16x8 qf[8];
#pragma unroll
  for (int c = 0; c < 8; ++c) {
    int d = c * 32 + quad * 8;
    const bf16* src = (d < 128) ? (q_c + (size_t)qrow * 2048 + h * 128 + d)
                                : (q_r + (size_t)qrow * 2048 + h * 128 + d - 128);
    qf[c] = *(const bf16x8*)src;
  }

  f32x4 o[8] = {};
  float mrow[4] = {-3e38f, -3e38f, -3e38f, -3e38f};
  float lrow[4] = {0.f, 0.f, 0.f, 0.f};

  const int ksr = lane >> 5;          // Ks chunk: 2 rows of 512B
  const int vsr = lane >> 3;          // Vs chunk: 8 rows of 128B

  for (int kt = 0; kt <= qt; ++kt) {
#pragma unroll
    for (int j = 0; j < 8; ++j) {
      int ch = w * 8 + j;
      int srow = ch * 2 + ksr;                   // local K row 0..63
      int slot = (lane & 31) ^ (srow & 7);       // swizzled 16B slot 0..31
      int d = slot * 8;                          // elem col in 256-dim
      const bf16* src = (d < 128)
          ? (k_c + (size_t)(kt * 64 + srow) * 2048 + h * 128 + d)
          : (k_r + (size_t)(kt * 64 + srow) * 128 + d - 128);
      async16(src, &Ks[ch * 512]);
    }
#pragma unroll
    for (int j = 0; j < 4; ++j) {
      int ch = w * 4 + j;
      int vrow = ch * 8 + vsr;                   // local d row 0..127
      int vs2 = ((lane & 7) ^ (vsr & 7)) * 8;    // swizzled s-elem
      async16(v_t + (size_t)(h * 128 + vrow) * 2048 + kt * 64 + vs2, &Vs[ch * 512]);
    }
    __syncthreads();

    // S = Q K^T  (wave's 16 q-rows x 64 k-cols); Ks read with XOR swizzle
    f32x4 sa[4] = {};
#pragma unroll
    for (int c = 0; c < 8; ++c) {
#pragma unroll
      for (int ks = 0; ks < 4; ++ks) {
        bf16x8 kf = *(const bf16x8*)&Ks[(ks * 16 + lm) * 256 +
                                        (((c * 4 + quad) ^ lm7) * 8)];
        sa[ks] = __builtin_amdgcn_mfma_f32_16x16x32_bf16(qf[c], kf, sa[ks], 0, 0, 0);
      }
    }
#pragma unroll
    for (int ks = 0; ks < 4; ++ks)
#pragma unroll
      for (int r = 0; r < 4; ++r)
        sa[ks][r] *= 0.0625f;  // 1/sqrt(2*DH)
    if (kt == qt) {            // diagonal tile: elementwise causal mask
#pragma unroll
      for (int ks = 0; ks < 4; ++ks)
#pragma unroll
        for (int r = 0; r < 4; ++r)
          if (ks * 16 + lm > w * 16 + quad * 4 + r) sa[ks][r] = -1e30f;
    }
    // online softmax; C-layout row = quad*4+reg, row-reduce = 16-lane shuffle
    float mx[4], alpha[4], rs[4];
#pragma unroll
    for (int r = 0; r < 4; ++r)
      mx[r] = fmaxf(fmaxf(sa[0][r], sa[1][r]), fmaxf(sa[2][r], sa[3][r]));
#pragma unroll
    for (int d = 1; d < 16; d <<= 1)
#pragma unroll
      for (int r = 0; r < 4; ++r)
        mx[r] = fmaxf(mx[r], __shfl_xor(mx[r], d, 64));
#pragma unroll
    for (int r = 0; r < 4; ++r) {
      float mn = fmaxf(mrow[r], mx[r]);
      alpha[r] = __expf(mrow[r] - mn);
      mrow[r] = mn;
      rs[r] = 0.f;
    }
#pragma unroll
    for (int ks = 0; ks < 4; ++ks)
#pragma unroll
      for (int r = 0; r < 4; ++r) {
        float p = __expf(sa[ks][r] - mrow[r]);
        rs[r] += p;
        int prow = w * 16 + quad * 4 + r;
        int pslot = (ks * 2 + (lm >> 3)) ^ (prow & 7);   // swizzled store slot
        Ps[prow * 64 + pslot * 8 + lm7] = f2bf(p);
      }
#pragma unroll
    for (int d = 1; d < 16; d <<= 1)
#pragma unroll
      for (int r = 0; r < 4; ++r)
        rs[r] += __shfl_xor(rs[r], d, 64);
#pragma unroll
    for (int r = 0; r < 4; ++r)
      lrow[r] = lrow[r] * alpha[r] + rs[r];
#pragma unroll
    for (int d8 = 0; d8 < 8; ++d8)
#pragma unroll
      for (int r = 0; r < 4; ++r)
        o[d8][r] *= alpha[r];
    __syncthreads();  // P visible (and orders vs other waves)

    // O += P @ V  (P from LDS as A-operand; V^T rows are d, contiguous s)
    bf16x8 pf[2];
#pragma unroll
    for (int kc = 0; kc < 2; ++kc)
      pf[kc] = *(const bf16x8*)&Ps[(w * 16 + lm) * 64 +
                                   (((kc * 4 + quad) ^ lm7) * 8)];
#pragma unroll
    for (int d8 = 0; d8 < 8; ++d8) {
#pragma unroll
      for (int kc = 0; kc < 2; ++kc) {
        bf16x8 vf = *(const bf16x8*)&Vs[(d8 * 16 + lm) * 64 +
                                        (((kc * 4 + quad) ^ lm7) * 8)];
        o[d8] = __builtin_amdgcn_mfma_f32_16x16x32_bf16(pf[kc], vf, o[d8], 0, 0, 0);
      }
    }
    __syncthreads();  // before next staging overwrites Ks/Vs
  }

  float inv_l[4];
#pragma unroll
  for (int r = 0; r < 4; ++r) inv_l[r] = 1.0f / lrow[r];
  bf16* Os = Ks;  // reuse 32KB as [64][128] output staging
#pragma unroll
  for (int d8 = 0; d8 < 8; ++d8)
#pragma unroll
    for (int r = 0; r < 4; ++r)
      Os[(w * 16 + quad * 4 + r) * 128 + d8 * 16 + lm] = f2bf(o[d8][r] * inv_l[r]);
  __syncthreads();
#pragma unroll
  for (int it = 0; it < 4; ++it) {
    int u = it * 256 + tid;
    int row = u >> 4, cb = u & 15;
    *(uint4*)(out_h + (size_t)(qt * 64 + row) * 2048 + h * 128 + cb * 8) =
        *(const uint4*)&Os[row * 128 + cb * 8];
  }
}

extern "C" void kernel_launch(void* const* d_in, const int* in_sizes, int n_in,
                              void* d_out, int out_size, void* d_ws, size_t ws_size,
                              hipStream_t stream) {
  const float* x    = (const float*)d_in[0];
  const float* Wdq  = (const float*)d_in[1];
  const float* Wdkv = (const float*)d_in[2];
  const float* Wuk  = (const float*)d_in[3];
  const float* Wuv  = (const float*)d_in[4];
  const float* Wuq  = (const float*)d_in[5];
  const float* Wqr  = (const float*)d_in[6];
  const float* Wkr  = (const float*)d_in[7];
  const float* Wo   = (const float*)d_in[8];
  const float* g_kv = (const float*)d_in[9];
  const float* b_kv = (const float*)d_in[10];
  const float* g_kr = (const float*)d_in[11];
  const float* b_kr = (const float*)d_in[12];

  float* out   = (float*)d_out;          // (2048, 32000)
  float* o_ckv = out + 65536000;         // (2048, 512)
  float* o_krh = o_ckv + 1048576;        // (2048, 16, 128)

  char* ws = (char*)d_ws;
  const size_t MB = 1ull << 20;
  // Early-phase buffers live in [0, 83MB). W_o^T (125MB) reuses [0,125MB) after
  // attention (all earlier buffers dead). out_heads at 126MB. Peak = 134MB.
  // WdqT / WdkvT / WkrT are contiguous: [1152][2048] for the merged down-proj.
  bf16*  x_bf   = (bf16*)(ws + 0);
  bf16*  WdqT   = (bf16*)(ws + 8 * MB);   // [512][2048]
  bf16*  WdkvT  = (bf16*)(ws + 10 * MB);  // [512][2048]
  bf16*  WkrT   = (bf16*)(ws + 12 * MB);  // [128][2048]
  bf16*  WuqT   = (bf16*)(ws + 13 * MB);
  bf16*  WukT   = (bf16*)(ws + 15 * MB);
  bf16*  WuvT   = (bf16*)(ws + 17 * MB);
  bf16*  WqrT   = (bf16*)(ws + 19 * MB);
  float* a_all  = (float*)(ws + 21 * MB); // (2048, 1152) = 9MB, ends at 30MB
  bf16*  cq_bf  = (bf16*)(ws + 30 * MB);
  bf16*  ckv_bf = (bf16*)(ws + 32 * MB);
  bf16*  kr_bf  = (bf16*)(ws + 34 * MB);
  bf16*  q_c    = (bf16*)(ws + 35 * MB);
  float* qrpre  = (float*)(ws + 43 * MB);
  bf16*  q_r    = (bf16*)(ws + 59 * MB);
  bf16*  k_c    = (bf16*)(ws + 67 * MB);
  bf16*  v_t    = (bf16*)(ws + 75 * MB);
  bf16*  WoT    = (bf16*)(ws + 0);
  bf16*  out_h  = (bf16*)(ws + 126 * MB);

  // 1) dtype conversion / weight transposes
  k_convert<<<4096, 256, 0, stream>>>(x, x_bf, 1048576);
  k_transpose<<<dim3(16, 64), 256, 0, stream>>>(Wdq, WdqT, 2048, 512);
  k_transpose<<<dim3(16, 64), 256, 0, stream>>>(Wdkv, WdkvT, 2048, 512);
  k_transpose<<<dim3(4, 64), 256, 0, stream>>>(Wkr, WkrT, 2048, 128);
  k_transpose<<<dim3(64, 16), 256, 0, stream>>>(Wuq, WuqT, 512, 2048);
  k_transpose<<<dim3(64, 16), 256, 0, stream>>>(Wuk, WukT, 512, 2048);
  k_transpose<<<dim3(64, 16), 256, 0, stream>>>(Wuv, WuvT, 512, 2048);
  k_transpose<<<dim3(64, 16), 256, 0, stream>>>(Wqr, WqrT, 512, 2048);

  // 2) merged down-projection (K=2048): [dq | dkv | kr] in one GEMM, N=1152
  k_gemm<float, false><<<dim3(16, 9), 256, 0, stream>>>(x_bf, WdqT, a_all, 2048, 1152, 2048);

  // 3) layernorms (c_kv and k_r_h go straight to d_out); inputs strided in a_all
  k_ln<<<2048, 64, 0, stream>>>(a_all +    0, g_kv, b_kv, cq_bf, (float*)nullptr, 512, 1152, 1);
  k_ln<<<2048, 64, 0, stream>>>(a_all +  512, g_kv, b_kv, ckv_bf, o_ckv, 512, 1152, 1);
  k_ln<<<2048, 64, 0, stream>>>(a_all + 1024, g_kr, b_kr, kr_bf, o_krh, 128, 1152, 16);

  // 4) up-projections (K=512); V written transposed (d, s) for PV B-operand
  k_gemm<bf16, false><<<dim3(16, 16), 256, 0, stream>>>(cq_bf, WuqT, q_c, 2048, 2048, 512);
  k_gemm<float, false><<<dim3(16, 16), 256, 0, stream>>>(cq_bf, WqrT, qrpre, 2048, 2048, 512);
  k_gemm<bf16, false><<<dim3(16, 16), 256, 0, stream>>>(ckv_bf, WukT, k_c, 2048, 2048, 512);
  k_gemm<bf16, true><<<dim3(16, 16), 256, 0, stream>>>(ckv_bf, WuvT, v_t, 2048, 2048, 512);

  // 5) rope on full 2048-dim rows
  k_rope<<<2048, 256, 0, stream>>>(qrpre, q_r);

  // 6) fused causal attention -> out_heads
  k_attn<<<512, 256, 0, stream>>>(q_c, q_r, k_c, kr_bf, v_t, out_h);

  // 7) vocab projection (dominant GEMM): transpose W_o (reusing dead ws), then
  //    256x256 8-phase pipelined GEMM (grid 8x125 = 1000, %8==0 for T1 swizzle)
  k_transpose<<<dim3(1000, 64), 256, 0, stream>>>(Wo, WoT, 2048, 32000);
  k_gemm256<<<1000, 512, 0, stream>>>(out_h, WoT, out, 2048, 32000, 2048);

  (void)in_sizes; (void)n_in; (void)out_size; (void)ws_size;
}